// Round 1
// baseline (1361.810 us; speedup 1.0000x reference)
//
#include <hip/hip_runtime.h>
#include <stdint.h>

#define BT 2048
#define H  2048
#define V  32000

typedef __attribute__((ext_vector_type(8))) short short8;
typedef __attribute__((ext_vector_type(4))) float f32x4;

__device__ inline unsigned short f2bf(float x) {
  unsigned int u = __float_as_uint(x);
  u += 0x7FFFu + ((u >> 16) & 1u);   // round-to-nearest-even
  return (unsigned short)(u >> 16);
}

// ---------------- kernel 0: zero the accumulator ----------------
__global__ void zero_accum(float* accum) {
  accum[0] = 0.0f;
  ((unsigned int*)accum)[1] = 0u;
}

// ---------------- kernel 1: fp32 -> bf16 convert (8 elems/thread) ----------------
__global__ __launch_bounds__(256) void cvt_kernel(const float* __restrict__ src,
                                                  unsigned short* __restrict__ dst,
                                                  int n8) {
  int i = blockIdx.x * blockDim.x + threadIdx.x;
  if (i >= n8) return;
  const float4* s = (const float4*)src;
  float4 a = s[2 * i];
  float4 b = s[2 * i + 1];
  union { unsigned short us[8]; uint4 v; } o;
  o.us[0] = f2bf(a.x); o.us[1] = f2bf(a.y); o.us[2] = f2bf(a.z); o.us[3] = f2bf(a.w);
  o.us[4] = f2bf(b.x); o.us[5] = f2bf(b.y); o.us[6] = f2bf(b.z); o.us[7] = f2bf(b.w);
  ((uint4*)dst)[i] = o.v;
}

// ---------------- kernel 2: bf16 NT GEMM (C = A @ B^T), 128x128 tile, BK=32 ----------------
// A: [BT,H] row-major, B: [V,H] row-major (K contiguous in both), C: [BT,V] bf16
#define BM 128
#define BN 128
#define BK 32

__global__ __launch_bounds__(256) void gemm_bt(const unsigned short* __restrict__ A0,
                                               const unsigned short* __restrict__ B0,
                                               const unsigned short* __restrict__ A1,
                                               const unsigned short* __restrict__ B1,
                                               unsigned short* __restrict__ C0,
                                               unsigned short* __restrict__ C1) {
  const int z = blockIdx.z;
  const unsigned short* A = z ? A1 : A0;
  const unsigned short* B = z ? B1 : B0;
  unsigned short* C = z ? C1 : C0;

  const int m0 = blockIdx.x * BM;   // BT tile
  const int n0 = blockIdx.y * BN;   // V tile

  __shared__ alignas(16) unsigned short lA[BM * BK];
  __shared__ alignas(16) unsigned short lB[BN * BK];

  const int tid  = threadIdx.x;
  const int lane = tid & 63;
  const int w    = tid >> 6;        // wave id 0..3
  const int wm   = w & 1;           // wave row (0..1)
  const int wn   = w >> 1;          // wave col (0..1)

  f32x4 acc[4][4];
  #pragma unroll
  for (int i = 0; i < 4; i++)
    #pragma unroll
    for (int j = 0; j < 4; j++)
      acc[i][j] = (f32x4){0.f, 0.f, 0.f, 0.f};

  const int q  = lane >> 4;         // quad 0..3
  const int l4 = lane & 15;

  for (int k0 = 0; k0 < H; k0 += BK) {
    // ---- stage A-tile and B-tile into LDS via async global->LDS (16B/lane) ----
    #pragma unroll
    for (int i = 0; i < 2; i++) {
      int basec = (i * 4 + w) * 64;            // wave-uniform base chunk (16B units)
      int c     = basec + lane;                // this lane's chunk
      int row   = c >> 2;                      // 0..127
      int cq    = c & 3;                       // k-chunk 0..3
      const unsigned short* ga = A + (size_t)(m0 + row) * H + k0 + cq * 8;
      const unsigned short* gb = B + (size_t)(n0 + row) * H + k0 + cq * 8;
      __builtin_amdgcn_global_load_lds(
          (const __attribute__((address_space(1))) unsigned int*)ga,
          (__attribute__((address_space(3))) unsigned int*)&lA[basec * 8], 16, 0, 0);
      __builtin_amdgcn_global_load_lds(
          (const __attribute__((address_space(1))) unsigned int*)gb,
          (__attribute__((address_space(3))) unsigned int*)&lB[basec * 8], 16, 0, 0);
    }
    __syncthreads();

    // ---- LDS -> fragments (ds_read_b128) ----
    short8 af[4], bf[4];
    #pragma unroll
    for (int mi = 0; mi < 4; mi++) {
      int M = wm * 64 + mi * 16 + l4;
      af[mi] = *(const short8*)&lA[(M * 4 + q) * 8];
    }
    #pragma unroll
    for (int ni = 0; ni < 4; ni++) {
      int N = wn * 64 + ni * 16 + l4;
      bf[ni] = *(const short8*)&lB[(N * 4 + q) * 8];
    }

    // ---- 16 MFMAs ----
    #pragma unroll
    for (int mi = 0; mi < 4; mi++)
      #pragma unroll
      for (int ni = 0; ni < 4; ni++)
        acc[mi][ni] = __builtin_amdgcn_mfma_f32_16x16x32_bf16(af[mi], bf[ni], acc[mi][ni], 0, 0, 0);

    __syncthreads();
  }

  // ---- epilogue: C/D layout col=lane&15, row=quad*4+reg (m89-verified) ----
  #pragma unroll
  for (int mi = 0; mi < 4; mi++)
    #pragma unroll
    for (int ni = 0; ni < 4; ni++)
      #pragma unroll
      for (int r = 0; r < 4; r++) {
        int gr = m0 + wm * 64 + mi * 16 + q * 4 + r;
        int gc = n0 + wn * 64 + ni * 16 + l4;
        C[(size_t)gr * V + gc] = f2bf(acc[mi][ni][r]);
      }
}

// ---------------- kernel 3: per-row JSD ----------------
__device__ inline void unpack8(uint4 v, float* f) {
  f[0] = __uint_as_float(v.x << 16);
  f[1] = __uint_as_float(v.x & 0xFFFF0000u);
  f[2] = __uint_as_float(v.y << 16);
  f[3] = __uint_as_float(v.y & 0xFFFF0000u);
  f[4] = __uint_as_float(v.z << 16);
  f[5] = __uint_as_float(v.z & 0xFFFF0000u);
  f[6] = __uint_as_float(v.w << 16);
  f[7] = __uint_as_float(v.w & 0xFFFF0000u);
}

__device__ inline float blk_max(float v, float* red, int tid) {
  #pragma unroll
  for (int o = 32; o > 0; o >>= 1) v = fmaxf(v, __shfl_xor(v, o, 64));
  __syncthreads();
  if ((tid & 63) == 0) red[tid >> 6] = v;
  __syncthreads();
  return fmaxf(fmaxf(red[0], red[1]), fmaxf(red[2], red[3]));
}

__device__ inline float blk_sum(float v, float* red, int tid) {
  #pragma unroll
  for (int o = 32; o > 0; o >>= 1) v += __shfl_xor(v, o, 64);
  __syncthreads();
  if ((tid & 63) == 0) red[tid >> 6] = v;
  __syncthreads();
  return (red[0] + red[1]) + (red[2] + red[3]);
}

__global__ __launch_bounds__(256) void jsd_kernel(const unsigned short* __restrict__ Slog,
                                                  const unsigned short* __restrict__ Tlog,
                                                  const long long* __restrict__ labels,
                                                  float* __restrict__ accum) {
  const int r   = blockIdx.x;
  const int tid = threadIdx.x;
  __shared__ float red[4];

  const uint4* s4 = (const uint4*)(Slog + (size_t)r * V);
  const uint4* t4 = (const uint4*)(Tlog + (size_t)r * V);
  const int NC = V / 8;   // 4000 chunks of 8 bf16

  // pass 1: maxes
  float smax = -1e30f, tmax = -1e30f;
  for (int c = tid; c < NC; c += 256) {
    uint4 sv = s4[c], tv = t4[c];
    float fs[8], ft[8];
    unpack8(sv, fs); unpack8(tv, ft);
    #pragma unroll
    for (int j = 0; j < 8; j++) {
      smax = fmaxf(smax, fs[j]);
      tmax = fmaxf(tmax, ft[j]);
    }
  }
  smax = blk_max(smax, red, tid);
  tmax = blk_max(tmax, red, tid);

  // pass 2: sum of exp
  float ssum = 0.f, tsum = 0.f;
  for (int c = tid; c < NC; c += 256) {
    uint4 sv = s4[c], tv = t4[c];
    float fs[8], ft[8];
    unpack8(sv, fs); unpack8(tv, ft);
    #pragma unroll
    for (int j = 0; j < 8; j++) {
      ssum += __expf(fs[j] - smax);
      tsum += __expf(ft[j] - tmax);
    }
  }
  ssum = blk_sum(ssum, red, tid);
  tsum = blk_sum(tsum, red, tid);
  float slse = smax + __logf(ssum);
  float tlse = tmax + __logf(tsum);

  // pass 3: JSD terms (beta = 0.5)
  float loss = 0.f;
  for (int c = tid; c < NC; c += 256) {
    uint4 sv = s4[c], tv = t4[c];
    float fs[8], ft[8];
    unpack8(sv, fs); unpack8(tv, ft);
    #pragma unroll
    for (int j = 0; j < 8; j++) {
      float sl = fs[j] - slse;        // log Q
      float tl = ft[j] - tlse;        // log P
      float qv = __expf(sl);
      float pv = __expf(tl);
      float m  = 0.5f * (pv + qv);
      float lm = __logf(m);
      loss += 0.5f * (pv * (tl - lm) + qv * (sl - lm));
    }
  }
  loss = blk_sum(loss, red, tid);

  if (tid == 0) {
    long long lab = labels[r];
    if (lab != -100LL) {
      atomicAdd(&accum[0], loss);
      atomicAdd((unsigned int*)&accum[1], 1u);
    }
  }
}

// ---------------- kernel 4: finalize ----------------
__global__ void finalize(const float* __restrict__ accum, float* __restrict__ out) {
  float cnt = (float)((const unsigned int*)accum)[1];
  out[0] = accum[0] / fmaxf(cnt, 1.0f);
}

extern "C" void kernel_launch(void* const* d_in, const int* in_sizes, int n_in,
                              void* d_out, int out_size, void* d_ws, size_t ws_size,
                              hipStream_t stream) {
  const float* s_in = (const float*)d_in[0];
  const float* s_w  = (const float*)d_in[1];
  const float* t_in = (const float*)d_in[2];
  const float* t_w  = (const float*)d_in[3];
  const long long* labels = (const long long*)d_in[4];
  float* out = (float*)d_out;

  // workspace layout
  char* ws = (char*)d_ws;
  size_t off = 0;
  auto take = [&](size_t bytes) -> char* {
    char* p = ws + off;
    off += (bytes + 255) & ~(size_t)255;
    return p;
  };
  unsigned short* sw_bf = (unsigned short*)take((size_t)V * H * 2);
  unsigned short* tw_bf = (unsigned short*)take((size_t)V * H * 2);
  unsigned short* si_bf = (unsigned short*)take((size_t)BT * H * 2);
  unsigned short* ti_bf = (unsigned short*)take((size_t)BT * H * 2);
  unsigned short* slog  = (unsigned short*)take((size_t)BT * V * 2);
  unsigned short* tlog  = (unsigned short*)take((size_t)BT * V * 2);
  float* accum = (float*)take(256);
  if (off > ws_size) return;  // workspace too small: bail (will show as wrong answer)

  zero_accum<<<dim3(1), dim3(1), 0, stream>>>(accum);

  const int nW8 = (V * H) / 8;   // 8,192,000
  const int nI8 = (BT * H) / 8;  // 524,288
  cvt_kernel<<<dim3((nW8 + 255) / 256), dim3(256), 0, stream>>>(s_w, sw_bf, nW8);
  cvt_kernel<<<dim3((nW8 + 255) / 256), dim3(256), 0, stream>>>(t_w, tw_bf, nW8);
  cvt_kernel<<<dim3((nI8 + 255) / 256), dim3(256), 0, stream>>>(s_in, si_bf, nI8);
  cvt_kernel<<<dim3((nI8 + 255) / 256), dim3(256), 0, stream>>>(t_in, ti_bf, nI8);

  gemm_bt<<<dim3(BT / BM, V / BN, 2), dim3(256), 0, stream>>>(si_bf, sw_bf, ti_bf, tw_bf, slog, tlog);

  jsd_kernel<<<dim3(BT), dim3(256), 0, stream>>>(slog, tlog, labels, accum);

  finalize<<<dim3(1), dim3(1), 0, stream>>>(accum, out);
}